// Round 7
// baseline (266.460 us; speedup 1.0000x reference)
//
#include <hip/hip_runtime.h>
#include <math.h>

#define B_  4
#define L_  2048
#define H_  8
#define D_  64
#define U_  40
#define HD  (H_*D_)   // 512
#define KC  16        // K chunks per bh in attention (128 keys each)

// ws layout (bytes): pacc[1280*64 f32]@0, pl[1280 f32]@327680,
// vmean[2048 f32]@332800  (memset 0..340992), M[65536 f32]@344064,
// mtop[1280 i32]@606208.  Total 611,328 B (< r5's proven ~2 MB).
#define OFF_PACC  0
#define OFF_PL    327680
#define OFF_VMEAN 332800
#define ZERO_BYTES 340992
#define OFF_M     344064
#define OFF_MTOP  606208

// ---------------------------------------------------------------------------
// threefry2x32 (jax partitionable stream) — verified bit-exact round 4.
// randint(key(42),(2048,40),0,2048) = tf(k2,(0,j)).b1 ^ .b2 & 2047 where
// k2 = tf((0,42),(0,1)) (second child of split), j = row*40+col.
// ---------------------------------------------------------------------------
struct U2 { unsigned a, b; };

__host__ __device__ constexpr unsigned rotl32c(unsigned x, int r){
  return (x<<r)|(x>>(32-r));
}

__host__ __device__ constexpr U2 tf2x32(unsigned k0, unsigned k1,
                                        unsigned x0, unsigned x1)
{
  const unsigned k2 = k0 ^ k1 ^ 0x1BD11BDAu;
  const int rA[4] = {13,15,26,6};
  const int rB[4] = {17,29,16,24};
  x0 += k0; x1 += k1;
  for (int i=0;i<4;i++){ x0+=x1; x1=rotl32c(x1,rA[i]); x1^=x0; }
  x0 += k1; x1 += k2 + 1u;
  for (int i=0;i<4;i++){ x0+=x1; x1=rotl32c(x1,rB[i]); x1^=x0; }
  x0 += k2; x1 += k0 + 2u;
  for (int i=0;i<4;i++){ x0+=x1; x1=rotl32c(x1,rA[i]); x1^=x0; }
  x0 += k0; x1 += k1 + 3u;
  for (int i=0;i<4;i++){ x0+=x1; x1=rotl32c(x1,rB[i]); x1^=x0; }
  x0 += k1; x1 += k2 + 4u;
  for (int i=0;i<4;i++){ x0+=x1; x1=rotl32c(x1,rA[i]); x1^=x0; }
  x0 += k2; x1 += k0 + 5u;
  return U2{x0, x1};
}

// ---------------------------------------------------------------------------
// Kernel 1: M[b,h,l] = max_s(q.k_s) - sum_s(q.k_s)/2048 over 40 sampled keys.
// One wave per (bh,l); 8 sample-groups x 8 lanes, coalesced 256 B row reads;
// idx computed inline (threefry). 512 consecutive blocks per bh -> each
// XCD L2 holds one 512 KB K slab at a time.
// ---------------------------------------------------------------------------
__global__ __launch_bounds__(256) void m_kernel(const float* __restrict__ q,
                                                const float* __restrict__ k,
                                                float*       __restrict__ M)
{
  int g    = blockIdx.x;        // 16384
  int bh   = g >> 9;
  int lblk = g & 511;
  int w    = threadIdx.x >> 6, lane = threadIdx.x & 63;
  int l    = lblk*4 + w;
  int b = bh >> 3, h = bh & 7;
  int grp  = lane >> 3;
  int l8   = lane & 7;
  const float* qrow = q + (size_t)(b*L_ + l)*HD + h*D_;
  float4 q0 = *(const float4*)(qrow + l8*8);
  float4 q1 = *(const float4*)(qrow + l8*8 + 4);
  constexpr U2 K2 = tf2x32(0u, 42u, 0u, 1u);
  int myidx = 0;
  if (lane < U_){
    U2 r = tf2x32(K2.a, K2.b, 0u, (unsigned)(l*U_ + lane));
    myidx = (int)((r.a ^ r.b) & 2047u);
  }
  const float* kbase = k + (size_t)b*L_*HD + h*D_;
  float vmax = -INFINITY, vsum = 0.f;
  #pragma unroll
  for (int t=0;t<5;t++){
    int s = t*8 + grp;
    int kidx = __shfl(myidx, s, 64);
    const float* krow = kbase + (size_t)kidx*HD;
    float4 k0 = *(const float4*)(krow + l8*8);
    float4 k1 = *(const float4*)(krow + l8*8 + 4);
    float p = q0.x*k0.x + q0.y*k0.y + q0.z*k0.z + q0.w*k0.w
            + q1.x*k1.x + q1.y*k1.y + q1.z*k1.z + q1.w*k1.w;
    p += __shfl_xor(p, 1, 64);
    p += __shfl_xor(p, 2, 64);
    p += __shfl_xor(p, 4, 64);
    vmax = fmaxf(vmax, p);
    vsum += p;
  }
  vmax = fmaxf(vmax, __shfl_xor(vmax, 8, 64));
  vmax = fmaxf(vmax, __shfl_xor(vmax,16, 64));
  vmax = fmaxf(vmax, __shfl_xor(vmax,32, 64));
  vsum += __shfl_xor(vsum, 8, 64);
  vsum += __shfl_xor(vsum,16, 64);
  vsum += __shfl_xor(vsum,32, 64);
  if (lane == 0) M[bh*L_ + l] = vmax - vsum * (1.0f/(float)L_);
}

// ---------------------------------------------------------------------------
// Kernel 2: top-40 per (b,h). 256 threads, LDS-resident M, 40x argmax.
// ---------------------------------------------------------------------------
__global__ __launch_bounds__(256) void topk_kernel(const float* __restrict__ M,
                                                   int* __restrict__ mtop)
{
  __shared__ float mv[L_];
  __shared__ float bv[4];
  __shared__ int   bix[4];
  int bh = blockIdx.x;
  int tid = threadIdx.x, w = tid >> 6, lane = tid & 63;
  for (int i=0;i<8;i++) mv[tid + 256*i] = M[bh*L_ + tid + 256*i];
  __syncthreads();
  for (int it=0; it<U_; ++it){
    float best = -INFINITY; int bi = 0x7fffffff;
    #pragma unroll
    for (int i=0;i<8;i++){
      float vv = mv[tid + 256*i];
      if (vv > best){ best = vv; bi = tid + 256*i; }
    }
    #pragma unroll
    for (int off=32; off; off>>=1){
      float ov = __shfl_xor(best, off, 64);
      int   oi = __shfl_xor(bi,   off, 64);
      if (ov > best || (ov == best && oi < bi)){ best = ov; bi = oi; }
    }
    if (lane == 0){ bv[w] = best; bix[w] = bi; }
    __syncthreads();
    if (tid == 0){
      float bb = bv[0]; int ii = bix[0];
      #pragma unroll
      for (int j=1;j<4;j++)
        if (bv[j] > bb || (bv[j] == bb && bix[j] < ii)){ bb = bv[j]; ii = bix[j]; }
      mtop[bh*U_ + it] = ii; mv[ii] = -INFINITY;
    }
    __syncthreads();
  }
}

// ---------------------------------------------------------------------------
// Kernel 3: V column sums (for mean), atomics into vmean (pre-zeroed).
// ---------------------------------------------------------------------------
__global__ __launch_bounds__(256) void vmean_kernel(const float* __restrict__ v,
                                                    float* __restrict__ vmean)
{
  int g = blockIdx.x;
  int bh = g & 31, chunk = g >> 5;
  int b = bh >> 3, h = bh & 7;
  int w = threadIdx.x >> 6, lane = threadIdx.x & 63;
  int l0 = chunk*128 + w*32;
  float s = 0.f;
  for (int i=0;i<32;i++)
    s += v[(size_t)(b*L_ + l0 + i)*HD + h*D_ + lane];
  atomicAdd(&vmean[bh*D_ + lane], s);
}

// ---------------------------------------------------------------------------
// Kernel 4: out[b][l][h][:] = V_mean (sum * 1/2048), float4 stores.
// ---------------------------------------------------------------------------
__global__ __launch_bounds__(256) void init_kernel(const float* __restrict__ vmean,
                                                   float* __restrict__ out)
{
  int i = blockIdx.x*256 + threadIdx.x;
  int d4 = i & 15;
  int h  = (i >> 4) & 7;
  int bl = i >> 7;
  int b  = bl >> 11;
  float4 vm = ((const float4*)(vmean + (b*H_ + h)*D_))[d4];
  const float sc = 1.0f/(float)L_;
  float4 o; o.x = vm.x*sc; o.y = vm.y*sc; o.z = vm.z*sc; o.w = vm.w*sc;
  ((float4*)out)[i] = o;
}

// ---------------------------------------------------------------------------
// Kernel 5: attention partials, NO max-subtraction (scores ~N(0,1), exp-safe
// in fp32; softmax is shift-invariant so result is identical). Grid = 512:
// bh = g&31, kc = g>>5 (128-key chunk). Block = 4 waves, LDS = Kt[128][68]
// + Qs[40][64] = 45 KB (3 blocks/CU capacity; r6 was 77.8 KB -> 2).
//   scores: wave w owns queries w*10..+9, lane owns keys {lane, lane+64}.
//   PV:     wave w owns keys [w*32,(w+1)*32), ALL 40 queries, lane = dim;
//           V read DIRECT from global (coalesced 256 B rows, read once) —
//           V never touches LDS. p transposed via psQ overlay on Kt.
// Partials (l, acc) merged across kc by global atomicAdd (pre-zeroed ws) —
// only 332 KB of workspace vs 5.24 MB for stored KC=16 partials.
// ---------------------------------------------------------------------------
__global__ __launch_bounds__(256) void attn_kernel(const float* __restrict__ q,
                                                   const float* __restrict__ k,
                                                   const float* __restrict__ v,
                                                   const int*   __restrict__ mtop,
                                                   float* __restrict__ pacc,
                                                   float* __restrict__ pl)
{
  __shared__ float sh[128*68 + 40*64];   // 45,056 B
  float* Kt  = sh;                        // psQ[40][128] overlays after scores
  float* Qs  = sh + 128*68;
  float* psQ = sh;

  int g  = blockIdx.x;
  int bh = g & 31, kc = g >> 5;
  int b = bh >> 3, h = bh & 7;
  int tid = threadIdx.x, w = tid >> 6, lane = tid & 63;
  int kt = kc*128;

  // stage K chunk (128 rows, padded 68) + Q (40 rows via mtop)
  #pragma unroll
  for (int c=0;c<8;c++){
    int flat = c*256 + tid;
    int row = flat >> 4, col = flat & 15;
    ((float4*)(Kt + row*68))[col] =
      ((const float4*)(k + (size_t)(b*L_ + kt + row)*HD + h*D_))[col];
  }
  #pragma unroll
  for (int c=0;c<3;c++){
    int flat = c*256 + tid;
    int row = flat >> 4, col = flat & 15;
    if (row < U_){
      int lstar = mtop[bh*U_ + row];
      ((float4*)(Qs + row*64))[col] =
        ((const float4*)(q + (size_t)(b*L_ + lstar)*HD + h*D_))[col];
    }
  }
  __syncthreads();

  // scores: 10 queries x 2 keys per lane
  float s0[10], s1[10];
  #pragma unroll
  for (int qq=0;qq<10;qq++){ s0[qq] = 0.f; s1[qq] = 0.f; }
  const float* kr0 = Kt + lane*68;
  const float* kr1 = Kt + (lane+64)*68;
  #pragma unroll
  for (int t=0;t<16;t++){
    float4 k0 = ((const float4*)kr0)[t];
    float4 k1 = ((const float4*)kr1)[t];
    #pragma unroll
    for (int qq=0;qq<10;qq++){
      float4 qf = ((const float4*)(Qs + (w*10+qq)*64))[t];
      s0[qq] += k0.x*qf.x + k0.y*qf.y + k0.z*qf.z + k0.w*qf.w;
      s1[qq] += k1.x*qf.x + k1.y*qf.y + k1.z*qf.z + k1.w*qf.w;
    }
  }
  __syncthreads();   // Kt reads done before psQ overlay

  // p = exp(s/8); accumulate l via wave-reduce + one atomic per query
  #pragma unroll
  for (int qq=0;qq<10;qq++){
    float p0 = __expf(s0[qq]*0.125f);
    float p1 = __expf(s1[qq]*0.125f);
    psQ[(w*10+qq)*128 + lane]      = p0;
    psQ[(w*10+qq)*128 + lane + 64] = p1;
    float ps = p0 + p1;
    #pragma unroll
    for (int off=32; off; off>>=1) ps += __shfl_xor(ps, off, 64);
    if (lane == 0) atomicAdd(&pl[bh*U_ + w*10 + qq], ps);
  }
  __syncthreads();   // psQ visible to all waves

  // PV: wave w owns keys [w*32, w*32+32), lane = output dim.
  float acc[40];
  #pragma unroll
  for (int qq=0;qq<40;qq++) acc[qq] = 0.f;
  const float* vbase = v + (size_t)(b*L_ + kt + w*32)*HD + h*D_ + lane;
  #pragma unroll
  for (int quad=0;quad<8;quad++){
    float v0 = vbase[(quad*4+0)*HD];
    float v1 = vbase[(quad*4+1)*HD];
    float v2 = vbase[(quad*4+2)*HD];
    float v3 = vbase[(quad*4+3)*HD];
    #pragma unroll
    for (int qq=0;qq<40;qq++){
      float4 pp = ((const float4*)(psQ + qq*128 + w*32))[quad];
      acc[qq] += pp.x*v0 + pp.y*v1 + pp.z*v2 + pp.w*v3;
    }
  }
  #pragma unroll
  for (int qq=0;qq<40;qq++)
    atomicAdd(&pacc[(size_t)(bh*U_ + qq)*64 + lane], acc[qq]);
}

// ---------------------------------------------------------------------------
// Kernel 6: normalize and scatter the 40 selected rows per (b,h).
// ---------------------------------------------------------------------------
__global__ __launch_bounds__(256) void combine_kernel(const int* __restrict__ mtop,
                                                      const float* __restrict__ pacc,
                                                      const float* __restrict__ pl,
                                                      float* __restrict__ out)
{
  int gu = blockIdx.x*4 + (threadIdx.x >> 6);  // 0..1279
  int lane = threadIdx.x & 63;
  int bh = gu / U_, u = gu - bh*U_;
  int b = bh >> 3, h = bh & 7;
  int lstar = mtop[bh*U_ + u];
  out[(size_t)(b*L_ + lstar)*HD + h*D_ + lane] =
      pacc[(size_t)gu*64 + lane] / pl[gu];
}

// ---------------------------------------------------------------------------
extern "C" void kernel_launch(void* const* d_in, const int* in_sizes, int n_in,
                              void* d_out, int out_size, void* d_ws, size_t ws_size,
                              hipStream_t stream)
{
  const float* q = (const float*)d_in[0];
  const float* k = (const float*)d_in[1];
  const float* v = (const float*)d_in[2];
  float* out = (float*)d_out;

  float* pacc  = (float*)((char*)d_ws + OFF_PACC);
  float* pl    = (float*)((char*)d_ws + OFF_PL);
  float* vmean = (float*)((char*)d_ws + OFF_VMEAN);
  float* M     = (float*)((char*)d_ws + OFF_M);
  int*   mtop  = (int*)  ((char*)d_ws + OFF_MTOP);

  hipMemsetAsync(d_ws, 0, ZERO_BYTES, stream);   // pacc + pl + vmean
  m_kernel      <<<16384, 256, 0, stream>>>(q, k, M);
  topk_kernel   <<<32,    256, 0, stream>>>(M, mtop);
  vmean_kernel  <<<512,   256, 0, stream>>>(v, vmean);
  init_kernel   <<<4096,  256, 0, stream>>>(vmean, out);
  attn_kernel   <<<512,   256, 0, stream>>>(q, k, v, mtop, pacc, pl);
  combine_kernel<<<320,   256, 0, stream>>>(mtop, pacc, pl, out);
}

// Round 8
// 262.623 us; speedup vs baseline: 1.0146x; 1.0146x over previous
//
#include <hip/hip_runtime.h>
#include <math.h>

#define B_  4
#define L_  2048
#define H_  8
#define D_  64
#define U_  40
#define HD  (H_*D_)   // 512

// ws layout (bytes): pacc[1280*64 f32]@0, pl[1280 f32]@327680,
// vmean[2048 f32]@332800  (memset 0..340992), M[65536 f32]@344064,
// mtop[1280 i32]@606208.  Total 611,328 B (proven safe in r7).
#define OFF_PACC  0
#define OFF_PL    327680
#define OFF_VMEAN 332800
#define ZERO_BYTES 340992
#define OFF_M     344064
#define OFF_MTOP  606208

// ---------------------------------------------------------------------------
// threefry2x32 (jax partitionable stream) — verified bit-exact round 4.
// randint(key(42),(2048,40),0,2048) = tf(k2,(0,j)).b1 ^ .b2 & 2047 where
// k2 = tf((0,42),(0,1)) (second child of split), j = row*40+col.
// ---------------------------------------------------------------------------
struct U2 { unsigned a, b; };

__host__ __device__ constexpr unsigned rotl32c(unsigned x, int r){
  return (x<<r)|(x>>(32-r));
}

__host__ __device__ constexpr U2 tf2x32(unsigned k0, unsigned k1,
                                        unsigned x0, unsigned x1)
{
  const unsigned k2 = k0 ^ k1 ^ 0x1BD11BDAu;
  const int rA[4] = {13,15,26,6};
  const int rB[4] = {17,29,16,24};
  x0 += k0; x1 += k1;
  for (int i=0;i<4;i++){ x0+=x1; x1=rotl32c(x1,rA[i]); x1^=x0; }
  x0 += k1; x1 += k2 + 1u;
  for (int i=0;i<4;i++){ x0+=x1; x1=rotl32c(x1,rB[i]); x1^=x0; }
  x0 += k2; x1 += k0 + 2u;
  for (int i=0;i<4;i++){ x0+=x1; x1=rotl32c(x1,rA[i]); x1^=x0; }
  x0 += k0; x1 += k1 + 3u;
  for (int i=0;i<4;i++){ x0+=x1; x1=rotl32c(x1,rB[i]); x1^=x0; }
  x0 += k1; x1 += k2 + 4u;
  for (int i=0;i<4;i++){ x0+=x1; x1=rotl32c(x1,rA[i]); x1^=x0; }
  x0 += k2; x1 += k0 + 5u;
  return U2{x0, x1};
}

// ---------------------------------------------------------------------------
// Kernel 1: M[b,h,l] = max_s(q.k_s) - sum_s(q.k_s)/2048 over 40 sampled keys.
// One wave per (bh,l); 8 sample-groups x 8 lanes, coalesced 256 B row reads;
// idx computed inline (threefry). 512 consecutive blocks per bh -> each
// XCD L2 holds one 512 KB K slab at a time.
// ---------------------------------------------------------------------------
__global__ __launch_bounds__(256) void m_kernel(const float* __restrict__ q,
                                                const float* __restrict__ k,
                                                float*       __restrict__ M)
{
  int g    = blockIdx.x;        // 16384
  int bh   = g >> 9;
  int lblk = g & 511;
  int w    = threadIdx.x >> 6, lane = threadIdx.x & 63;
  int l    = lblk*4 + w;
  int b = bh >> 3, h = bh & 7;
  int grp  = lane >> 3;
  int l8   = lane & 7;
  const float* qrow = q + (size_t)(b*L_ + l)*HD + h*D_;
  float4 q0 = *(const float4*)(qrow + l8*8);
  float4 q1 = *(const float4*)(qrow + l8*8 + 4);
  constexpr U2 K2 = tf2x32(0u, 42u, 0u, 1u);
  int myidx = 0;
  if (lane < U_){
    U2 r = tf2x32(K2.a, K2.b, 0u, (unsigned)(l*U_ + lane));
    myidx = (int)((r.a ^ r.b) & 2047u);
  }
  const float* kbase = k + (size_t)b*L_*HD + h*D_;
  float vmax = -INFINITY, vsum = 0.f;
  #pragma unroll
  for (int t=0;t<5;t++){
    int s = t*8 + grp;
    int kidx = __shfl(myidx, s, 64);
    const float* krow = kbase + (size_t)kidx*HD;
    float4 k0 = *(const float4*)(krow + l8*8);
    float4 k1 = *(const float4*)(krow + l8*8 + 4);
    float p = q0.x*k0.x + q0.y*k0.y + q0.z*k0.z + q0.w*k0.w
            + q1.x*k1.x + q1.y*k1.y + q1.z*k1.z + q1.w*k1.w;
    p += __shfl_xor(p, 1, 64);
    p += __shfl_xor(p, 2, 64);
    p += __shfl_xor(p, 4, 64);
    vmax = fmaxf(vmax, p);
    vsum += p;
  }
  vmax = fmaxf(vmax, __shfl_xor(vmax, 8, 64));
  vmax = fmaxf(vmax, __shfl_xor(vmax,16, 64));
  vmax = fmaxf(vmax, __shfl_xor(vmax,32, 64));
  vsum += __shfl_xor(vsum, 8, 64);
  vsum += __shfl_xor(vsum,16, 64);
  vsum += __shfl_xor(vsum,32, 64);
  if (lane == 0) M[bh*L_ + l] = vmax - vsum * (1.0f/(float)L_);
}

// ---------------------------------------------------------------------------
// Kernel 2: top-40 per (b,h). Per-thread running (max,idx) over its 8 slots
// kept in REGISTERS; per iteration only reduce 256 candidates + the single
// winner thread rescans its 8 slots (r7 version rescanned all 2048 slots
// every iteration -> 8x the LDS traffic and most of the kernel's time).
// ---------------------------------------------------------------------------
__global__ __launch_bounds__(256) void topk_kernel(const float* __restrict__ M,
                                                   int* __restrict__ mtop)
{
  __shared__ float mv[L_];
  __shared__ float bv[4];
  __shared__ int   bix[4];
  __shared__ int   wsh;
  int bh = blockIdx.x;
  int tid = threadIdx.x, w = tid >> 6, lane = tid & 63;
  float tb = -INFINITY; int ti = tid;
  #pragma unroll
  for (int i=0;i<8;i++){
    float vv = M[bh*L_ + tid + 256*i];
    mv[tid + 256*i] = vv;
    if (vv > tb){ tb = vv; ti = tid + 256*i; }
  }
  for (int it=0; it<U_; ++it){
    float best = tb; int bi = ti;
    #pragma unroll
    for (int off=32; off; off>>=1){
      float ov = __shfl_xor(best, off, 64);
      int   oi = __shfl_xor(bi,   off, 64);
      if (ov > best || (ov == best && oi < bi)){ best = ov; bi = oi; }
    }
    if (lane == 0){ bv[w] = best; bix[w] = bi; }
    __syncthreads();
    if (tid == 0){
      float bb = bv[0]; int ii = bix[0];
      #pragma unroll
      for (int j=1;j<4;j++)
        if (bv[j] > bb || (bv[j] == bb && bix[j] < ii)){ bb = bv[j]; ii = bix[j]; }
      mtop[bh*U_ + it] = ii; wsh = ii;
    }
    __syncthreads();
    int wi = wsh;
    if (ti == wi){          // unique owner of that slot
      mv[wi] = -INFINITY;
      tb = -INFINITY; ti = tid;
      #pragma unroll
      for (int i=0;i<8;i++){
        float vv = mv[tid + 256*i];
        if (vv > tb){ tb = vv; ti = tid + 256*i; }
      }
    }
  }
}

// ---------------------------------------------------------------------------
// Kernel 3: V column sums (for mean), atomics into vmean (pre-zeroed).
// ---------------------------------------------------------------------------
__global__ __launch_bounds__(256) void vmean_kernel(const float* __restrict__ v,
                                                    float* __restrict__ vmean)
{
  int g = blockIdx.x;
  int bh = g & 31, chunk = g >> 5;
  int b = bh >> 3, h = bh & 7;
  int w = threadIdx.x >> 6, lane = threadIdx.x & 63;
  int l0 = chunk*128 + w*32;
  float s = 0.f;
  for (int i=0;i<32;i++)
    s += v[(size_t)(b*L_ + l0 + i)*HD + h*D_ + lane];
  atomicAdd(&vmean[bh*D_ + lane], s);
}

// ---------------------------------------------------------------------------
// Kernel 4: out[b][l][h][:] = V_mean (sum * 1/2048), float4 stores.
// ---------------------------------------------------------------------------
__global__ __launch_bounds__(256) void init_kernel(const float* __restrict__ vmean,
                                                   float* __restrict__ out)
{
  int i = blockIdx.x*256 + threadIdx.x;
  int d4 = i & 15;
  int h  = (i >> 4) & 7;
  int bl = i >> 7;
  int b  = bl >> 11;
  float4 vm = ((const float4*)(vmean + (b*H_ + h)*D_))[d4];
  const float sc = 1.0f/(float)L_;
  float4 o; o.x = vm.x*sc; o.y = vm.y*sc; o.z = vm.z*sc; o.w = vm.w*sc;
  ((float4*)out)[i] = o;
}

// ---------------------------------------------------------------------------
// Kernel 5: attention partials. r6's spill-free register structure (VGPR 132,
// acc[10]/lane, Vt in LDS — r7's acc[40] hit VGPR=256 + 130 MB scratch spill)
// x KC=16 grid (512 blocks = 2/CU; r6 ran the KC=4 fallback with half the
// CUs idle) x r7's no-max softmax + atomicAdd merge (611 KB ws, proven).
// One 128-key tile per block: no online rescaling at all.
//   scores: wave w owns queries w*10..+9, lane owns keys {lane, lane+64}.
//   PV:     lane = output dim, acc[10] in registers, Vt quad loads shared
//           across the wave's 10 queries; psQ (p^T) overlays dead Kt.
// ---------------------------------------------------------------------------
__global__ __launch_bounds__(256) void attn_kernel(const float* __restrict__ q,
                                                   const float* __restrict__ k,
                                                   const float* __restrict__ v,
                                                   const int*   __restrict__ mtop,
                                                   float* __restrict__ pacc,
                                                   float* __restrict__ pl)
{
  __shared__ float sh[128*68 + 128*64 + 40*64];  // 77,824 B -> 2 blocks/CU
  float* Kt  = sh;                 // psQ[40][128] overlays after scores
  float* Vt  = sh + 128*68;
  float* Qs  = sh + 128*68 + 128*64;
  float* psQ = sh;

  int g  = blockIdx.x;             // 512
  int bh = g & 31, kc = g >> 5;
  int b = bh >> 3, h = bh & 7;
  int tid = threadIdx.x, w = tid >> 6, lane = tid & 63;
  int kt = kc*128;

  // stage K (128x64, pad 68), V (128x64), Q (40x64 via mtop)
  #pragma unroll
  for (int c=0;c<8;c++){
    int flat = c*256 + tid;
    int row = flat >> 4, col = flat & 15;
    ((float4*)(Kt + row*68))[col] =
      ((const float4*)(k + (size_t)(b*L_ + kt + row)*HD + h*D_))[col];
    ((float4*)(Vt + row*64))[col] =
      ((const float4*)(v + (size_t)(b*L_ + kt + row)*HD + h*D_))[col];
  }
  #pragma unroll
  for (int c=0;c<3;c++){
    int flat = c*256 + tid;
    int row = flat >> 4, col = flat & 15;
    if (row < U_){
      int lstar = mtop[bh*U_ + row];
      ((float4*)(Qs + row*64))[col] =
        ((const float4*)(q + (size_t)(b*L_ + lstar)*HD + h*D_))[col];
    }
  }
  __syncthreads();

  // scores: 10 queries x 2 keys per lane
  float s0[10], s1[10];
  #pragma unroll
  for (int qq=0;qq<10;qq++){ s0[qq] = 0.f; s1[qq] = 0.f; }
  const float* kr0 = Kt + lane*68;
  const float* kr1 = Kt + (lane+64)*68;
  #pragma unroll
  for (int t=0;t<16;t++){
    float4 k0 = ((const float4*)kr0)[t];
    float4 k1 = ((const float4*)kr1)[t];
    #pragma unroll
    for (int qq=0;qq<10;qq++){
      float4 qf = ((const float4*)(Qs + (w*10+qq)*64))[t];
      s0[qq] += k0.x*qf.x + k0.y*qf.y + k0.z*qf.z + k0.w*qf.w;
      s1[qq] += k1.x*qf.x + k1.y*qf.y + k1.z*qf.z + k1.w*qf.w;
    }
  }
  __syncthreads();   // Kt reads done before psQ overlay

  // p = exp(s/8) (no max-shift: s ~ N(0,1), fp32-safe; validated r7);
  // row-sum via wave-reduce + one atomic per query
  #pragma unroll
  for (int qq=0;qq<10;qq++){
    float p0 = __expf(s0[qq]*0.125f);
    float p1 = __expf(s1[qq]*0.125f);
    psQ[(w*10+qq)*128 + lane]      = p0;
    psQ[(w*10+qq)*128 + lane + 64] = p1;
    float ps = p0 + p1;
    #pragma unroll
    for (int off=32; off; off>>=1) ps += __shfl_xor(ps, off, 64);
    if (lane == 0) atomicAdd(&pl[bh*U_ + w*10 + qq], ps);
  }
  __syncthreads();   // psQ visible to all waves

  // PV: lane = output dim, wave w's 10 queries, all 128 keys from Vt
  float acc[10];
  #pragma unroll
  for (int qq=0;qq<10;qq++) acc[qq] = 0.f;
  for (int k4=0;k4<32;k4++){
    float v0 = Vt[(4*k4+0)*64 + lane];
    float v1 = Vt[(4*k4+1)*64 + lane];
    float v2 = Vt[(4*k4+2)*64 + lane];
    float v3 = Vt[(4*k4+3)*64 + lane];
    #pragma unroll
    for (int qq=0;qq<10;qq++){
      float4 pp = ((const float4*)(psQ + (w*10+qq)*128))[k4];
      acc[qq] += pp.x*v0 + pp.y*v1 + pp.z*v2 + pp.w*v3;
    }
  }
  #pragma unroll
  for (int qq=0;qq<10;qq++)
    atomicAdd(&pacc[(size_t)(bh*U_ + w*10 + qq)*64 + lane], acc[qq]);
}

// ---------------------------------------------------------------------------
// Kernel 6: normalize and scatter the 40 selected rows per (b,h).
// ---------------------------------------------------------------------------
__global__ __launch_bounds__(256) void combine_kernel(const int* __restrict__ mtop,
                                                      const float* __restrict__ pacc,
                                                      const float* __restrict__ pl,
                                                      float* __restrict__ out)
{
  int gu = blockIdx.x*4 + (threadIdx.x >> 6);  // 0..1279
  int lane = threadIdx.x & 63;
  int bh = gu / U_, u = gu - bh*U_;
  int b = bh >> 3, h = bh & 7;
  int lstar = mtop[bh*U_ + u];
  out[(size_t)(b*L_ + lstar)*HD + h*D_ + lane] =
      pacc[(size_t)gu*64 + lane] / pl[gu];
}

// ---------------------------------------------------------------------------
extern "C" void kernel_launch(void* const* d_in, const int* in_sizes, int n_in,
                              void* d_out, int out_size, void* d_ws, size_t ws_size,
                              hipStream_t stream)
{
  const float* q = (const float*)d_in[0];
  const float* k = (const float*)d_in[1];
  const float* v = (const float*)d_in[2];
  float* out = (float*)d_out;

  float* pacc  = (float*)((char*)d_ws + OFF_PACC);
  float* pl    = (float*)((char*)d_ws + OFF_PL);
  float* vmean = (float*)((char*)d_ws + OFF_VMEAN);
  float* M     = (float*)((char*)d_ws + OFF_M);
  int*   mtop  = (int*)  ((char*)d_ws + OFF_MTOP);

  hipMemsetAsync(d_ws, 0, ZERO_BYTES, stream);   // pacc + pl + vmean
  m_kernel      <<<16384, 256, 0, stream>>>(q, k, M);
  topk_kernel   <<<32,    256, 0, stream>>>(M, mtop);
  vmean_kernel  <<<512,   256, 0, stream>>>(v, vmean);
  init_kernel   <<<4096,  256, 0, stream>>>(vmean, out);
  attn_kernel   <<<512,   256, 0, stream>>>(q, k, v, mtop, pacc, pl);
  combine_kernel<<<320,   256, 0, stream>>>(mtop, pacc, pl, out);
}